// Round 2
// baseline (204.077 us; speedup 1.0000x reference)
//
#include <hip/hip_runtime.h>
#include <hip/hip_bf16.h>

#define NB 4
#define NH 12
#define SEQ 4096
#define DIM 64
#define BH (NB * NH)

typedef __attribute__((ext_vector_type(8))) short short8;
typedef __attribute__((ext_vector_type(4))) float f32x4;
typedef __attribute__((ext_vector_type(4))) unsigned short ushort4v;

static __device__ __forceinline__ unsigned short f2bf(float f) {
    unsigned int u = __builtin_bit_cast(unsigned int, f);
    u = u + 0x7FFFu + ((u >> 16) & 1u);   // RNE (inputs finite)
    return (unsigned short)(u >> 16);
}

static __device__ __forceinline__ void gld16(const void* g, void* l) {
    __builtin_amdgcn_global_load_lds(
        (const __attribute__((address_space(1))) unsigned int*)g,
        (__attribute__((address_space(3))) unsigned int*)l,
        16, 0, 0);
}

// ---------------- prepack: K -> bf16 cast, row-major ----------------
__global__ __launch_bounds__(256)
void prepack_k(const float* __restrict__ K, unsigned short* __restrict__ Kb) {
    size_t i = ((size_t)blockIdx.x * 256 + threadIdx.x) * 8;
    f32x4 a = *reinterpret_cast<const f32x4*>(K + i);
    f32x4 b = *reinterpret_cast<const f32x4*>(K + i + 4);
    short8 o;
    o[0] = (short)f2bf(a[0]); o[1] = (short)f2bf(a[1]);
    o[2] = (short)f2bf(a[2]); o[3] = (short)f2bf(a[3]);
    o[4] = (short)f2bf(b[0]); o[5] = (short)f2bf(b[1]);
    o[6] = (short)f2bf(b[2]); o[7] = (short)f2bf(b[3]);
    *reinterpret_cast<short8*>(Kb + i) = o;
}

// ---------------- prepack: V -> bf16 transposed [bh][64][SEQ] ----------------
__global__ __launch_bounds__(256)
void prepack_v(const float* __restrict__ V, unsigned short* __restrict__ Vb) {
    __shared__ unsigned short T[64][256];   // T[d][key ^ 8*((d>>2)&7)]
    const int bid = blockIdx.x;
    const int kt  = bid & 15;
    const int bh  = bid >> 4;
    const float* Vp = V + ((size_t)bh * SEQ + kt * 256) * DIM;
    const int tid = threadIdx.x;
    const int c   = tid & 15;
    const int c4  = c * 4;
    const int sw  = 8 * (c & 7);            // (d>>2)&7 == c for d = 4c+i
    #pragma unroll
    for (int rr = 0; rr < 16; ++rr) {
        const int key = (tid >> 4) + 16 * rr;
        f32x4 v = *reinterpret_cast<const f32x4*>(Vp + (size_t)key * DIM + c4);
        T[c4 + 0][key ^ sw] = f2bf(v[0]);
        T[c4 + 1][key ^ sw] = f2bf(v[1]);
        T[c4 + 2][key ^ sw] = f2bf(v[2]);
        T[c4 + 3][key ^ sw] = f2bf(v[3]);
    }
    __syncthreads();
    #pragma unroll
    for (int q = 0; q < 8; ++q) {
        const int d    = q * 8 + (tid >> 5);
        const int col0 = (tid & 31) * 8;
        const int swd  = 8 * ((d >> 2) & 7);
        short8 val = *reinterpret_cast<const short8*>(&T[d][col0 ^ swd]);
        *reinterpret_cast<short8*>(Vb + ((size_t)bh * DIM + d) * SEQ + kt * 256 + col0) = val;
    }
}

// ---------------- main attention kernel ----------------
__global__ __launch_bounds__(512, 4)
void blk_attn(const float* __restrict__ Q, const float* __restrict__ K,
              const float* __restrict__ V, const float* __restrict__ M,
              float* __restrict__ O,
              const unsigned short* __restrict__ Kb,
              const unsigned short* __restrict__ Vb, int use_pre) {
    int bid = blockIdx.x;
    bid = (bid & 7) * 192 + (bid >> 3);   // XCD-aware bijective swizzle (1536 % 8 == 0)

    const int j  = bid & 31;
    const int bh = bid >> 5;
    const int b  = bh / NH;

    const size_t base = (size_t)bh * SEQ * DIM;
    const float* Qp = Q + base + (size_t)j * 128 * DIM;
    const float* Kp = K + base;
    const float* Vp = V + base;
    const float* Mp = M + (size_t)b * SEQ;
    float*       Op = O + base + (size_t)j * 128 * DIM;
    const unsigned short* Kbp = Kb + base;
    const unsigned short* Vbp = Vb + base;   // [64][SEQ]

    const int tid  = threadIdx.x;
    const int wv   = tid >> 6;
    const int lane = tid & 63;
    const int lo   = lane & 15;
    const int hi   = lane >> 4;

    // 80 KB total -> 2 blocks/CU. All b128 reads conflict-free via XOR swizzle.
    __shared__ unsigned short Ks[256][64];   // Ks[key][d ^ 8*(key&7)]
    __shared__ unsigned short Vt[64][256];   // Vt[d][key ^ 8*(d&7)]
    __shared__ unsigned short Pw[8][16][64]; // Pw[wv][q][col ^ 8*(q&7)]

    // ---- Q fragments (scaled by 1/8), in regs ----
    short8 qa[2];
    {
        const float* qr = Qp + (size_t)(wv * 16 + lo) * DIM + hi * 8;
        #pragma unroll
        for (int s = 0; s < 2; ++s) {
            f32x4 a = *reinterpret_cast<const f32x4*>(qr + 32 * s);
            f32x4 c = *reinterpret_cast<const f32x4*>(qr + 32 * s + 4);
            short8 t;
            t[0] = (short)f2bf(a[0] * 0.125f);
            t[1] = (short)f2bf(a[1] * 0.125f);
            t[2] = (short)f2bf(a[2] * 0.125f);
            t[3] = (short)f2bf(a[3] * 0.125f);
            t[4] = (short)f2bf(c[0] * 0.125f);
            t[5] = (short)f2bf(c[1] * 0.125f);
            t[6] = (short)f2bf(c[2] * 0.125f);
            t[7] = (short)f2bf(c[3] * 0.125f);
            qa[s] = t;
        }
    }

    int nw, wb0, wb1; float wt;
    if (j == 0)       { nw = 1; wb0 = 0;             wb1 = 0;       wt = 1.0f; }
    else if (j == 31) { nw = 1; wb0 = 128 * 31 - 128; wb1 = 0;      wt = 1.0f; }
    else              { nw = 2; wb0 = 128 * j - 128;  wb1 = 128 * j; wt = 0.5f; }

    f32x4 fin[4];
    #pragma unroll
    for (int dt = 0; dt < 4; ++dt) { fin[dt][0]=0.f; fin[dt][1]=0.f; fin[dt][2]=0.f; fin[dt][3]=0.f; }

    for (int w = 0; w < nw; ++w) {
        const int kb = (w == 0) ? wb0 : wb1;

        __syncthreads();   // previous window's reads complete before restage
        if (use_pre) {
            // wave wv stages 4 K-chunks + 4 V-chunks via global_load_lds (16B/lane)
            #pragma unroll
            for (int tt = 0; tt < 4; ++tt) {
                const int t = wv * 4 + tt;
                {   // K: rows = keys, 8 rows per chunk
                    const int key = t * 8 + (lane >> 3);
                    const int col = ((lane & 7) * 8) ^ (8 * (key & 7));
                    gld16(Kbp + (size_t)(kb + key) * DIM + col,
                          (unsigned short*)Ks + t * 512);
                }
                {   // V: rows = d, 2 rows per chunk
                    const int d   = 2 * t + (lane >> 5);
                    const int col = ((lane & 31) * 8) ^ (8 * (d & 7));
                    gld16(Vbp + (size_t)d * SEQ + kb + col,
                          (unsigned short*)Vt + t * 512);
                }
            }
        } else {
            const int r0 = tid >> 4;
            const int c4 = (tid & 15) * 4;
            #pragma unroll
            for (int rr = 0; rr < 8; ++rr) {
                const int row = r0 + 32 * rr;
                f32x4 kv = *reinterpret_cast<const f32x4*>(Kp + (size_t)(kb + row) * DIM + c4);
                ushort4v kk;
                kk[0] = f2bf(kv[0]); kk[1] = f2bf(kv[1]); kk[2] = f2bf(kv[2]); kk[3] = f2bf(kv[3]);
                *reinterpret_cast<ushort4v*>(&Ks[row][c4 ^ (8 * (row & 7))]) = kk;
                f32x4 vv = *reinterpret_cast<const f32x4*>(Vp + (size_t)(kb + row) * DIM + c4);
                Vt[c4 + 0][row ^ (8 * ((c4 + 0) & 7))] = f2bf(vv[0]);
                Vt[c4 + 1][row ^ (8 * ((c4 + 1) & 7))] = f2bf(vv[1]);
                Vt[c4 + 2][row ^ (8 * ((c4 + 2) & 7))] = f2bf(vv[2]);
                Vt[c4 + 3][row ^ (8 * ((c4 + 3) & 7))] = f2bf(vv[3]);
            }
        }
        __syncthreads();   // drains vmcnt(0) + lgkmcnt(0)

        // ---- QK^T ----
        f32x4 st[16];
        #pragma unroll
        for (int t = 0; t < 16; ++t) { st[t][0]=0.f; st[t][1]=0.f; st[t][2]=0.f; st[t][3]=0.f; }
        #pragma unroll
        for (int s = 0; s < 2; ++s) {
            #pragma unroll
            for (int t = 0; t < 16; ++t) {
                short8 kf = *reinterpret_cast<const short8*>(
                    &Ks[t * 16 + lo][(s * 32 + hi * 8) ^ (8 * (lo & 7))]);
                st[t] = __builtin_amdgcn_mfma_f32_16x16x32_bf16(qa[s], kf, st[t], 0, 0, 0);
            }
        }
        // mask (per key; L1-resident)
        #pragma unroll
        for (int t = 0; t < 16; ++t) {
            const float mv = Mp[kb + t * 16 + lo];
            #pragma unroll
            for (int r = 0; r < 4; ++r) st[t][r] += mv;
        }

        // ---- softmax over 256 keys ----
        float mx[4], dn[4];
        #pragma unroll
        for (int r = 0; r < 4; ++r) {
            float m = st[0][r];
            #pragma unroll
            for (int t = 1; t < 16; ++t) m = fmaxf(m, st[t][r]);
            m = fmaxf(m, __shfl_xor(m, 1));
            m = fmaxf(m, __shfl_xor(m, 2));
            m = fmaxf(m, __shfl_xor(m, 4));
            m = fmaxf(m, __shfl_xor(m, 8));
            mx[r] = m;
            dn[r] = 0.f;
        }
        #pragma unroll
        for (int t = 0; t < 16; ++t) {
            #pragma unroll
            for (int r = 0; r < 4; ++r) {
                const float p = __expf(st[t][r] - mx[r]);
                st[t][r] = p;
                dn[r] += p;
            }
        }
        #pragma unroll
        for (int r = 0; r < 4; ++r) {
            dn[r] += __shfl_xor(dn[r], 1);
            dn[r] += __shfl_xor(dn[r], 2);
            dn[r] += __shfl_xor(dn[r], 4);
            dn[r] += __shfl_xor(dn[r], 8);
        }

        // ---- PV in 4 quarters of 64 keys ----
        f32x4 ow[4];
        #pragma unroll
        for (int dt = 0; dt < 4; ++dt) { ow[dt][0]=0.f; ow[dt][1]=0.f; ow[dt][2]=0.f; ow[dt][3]=0.f; }

        #pragma unroll
        for (int kq = 0; kq < 4; ++kq) {
            #pragma unroll
            for (int tt = 0; tt < 4; ++tt) {
                const int t = 4 * kq + tt;
                #pragma unroll
                for (int r = 0; r < 4; ++r) {
                    const int q = 4 * hi + r;
                    Pw[wv][q][(tt * 16 + lo) ^ (8 * (q & 7))] = f2bf(st[t][r]);
                }
            }
            // per-wave DS ops are in-order; compiler inserts lgkmcnt before MFMA use
            #pragma unroll
            for (int s = 0; s < 2; ++s) {
                short8 pf = *reinterpret_cast<const short8*>(
                    &Pw[wv][lo][(s * 32 + hi * 8) ^ (8 * (lo & 7))]);
                #pragma unroll
                for (int dt = 0; dt < 4; ++dt) {
                    short8 vf = *reinterpret_cast<const short8*>(
                        &Vt[dt * 16 + lo][(kq * 64 + s * 32 + hi * 8) ^ (8 * (lo & 7))]);
                    ow[dt] = __builtin_amdgcn_mfma_f32_16x16x32_bf16(pf, vf, ow[dt], 0, 0, 0);
                }
            }
        }

        float rs[4];
        #pragma unroll
        for (int r = 0; r < 4; ++r) rs[r] = wt / dn[r];
        #pragma unroll
        for (int dt = 0; dt < 4; ++dt)
            #pragma unroll
            for (int r = 0; r < 4; ++r)
                fin[dt][r] += ow[dt][r] * rs[r];
    }

    #pragma unroll
    for (int dt = 0; dt < 4; ++dt)
        #pragma unroll
        for (int r = 0; r < 4; ++r)
            Op[(size_t)(wv * 16 + hi * 4 + r) * DIM + dt * 16 + lo] = fin[dt][r];
}

extern "C" void kernel_launch(void* const* d_in, const int* in_sizes, int n_in,
                              void* d_out, int out_size, void* d_ws, size_t ws_size,
                              hipStream_t stream) {
    const float* Q = (const float*)d_in[0];
    const float* K = (const float*)d_in[1];
    const float* V = (const float*)d_in[2];
    const float* M = (const float*)d_in[3];
    float* O = (float*)d_out;

    const size_t PK_BYTES = (size_t)BH * SEQ * DIM * 2;   // 25,165,824
    const bool pre = ws_size >= 2 * PK_BYTES;
    unsigned short* Kb = (unsigned short*)d_ws;
    unsigned short* Vb = (unsigned short*)((char*)d_ws + PK_BYTES);

    if (pre) {
        prepack_k<<<dim3(BH * SEQ * DIM / (256 * 8)), dim3(256), 0, stream>>>(K, Kb);
        prepack_v<<<dim3(BH * (SEQ / 256)), dim3(256), 0, stream>>>(V, Vb);
    }
    blk_attn<<<dim3(BH * (SEQ / 128)), dim3(512), 0, stream>>>(Q, K, V, M, O, Kb, Vb, pre ? 1 : 0);
}

// Round 3
// 95.881 us; speedup vs baseline: 2.1284x; 2.1284x over previous
//
#include <hip/hip_runtime.h>
#include <hip/hip_bf16.h>

#define NB 4
#define NH 12
#define SEQ 4096
#define DIM 64

typedef __attribute__((ext_vector_type(8))) short short8;
typedef __attribute__((ext_vector_type(4))) float f32x4;
typedef __attribute__((ext_vector_type(4))) unsigned short ushort4v;

static __device__ __forceinline__ unsigned short f2bf(float f) {
    unsigned int u = __builtin_bit_cast(unsigned int, f);
    u = u + 0x7FFFu + ((u >> 16) & 1u);   // RNE (inputs finite)
    return (unsigned short)(u >> 16);
}

__global__ __launch_bounds__(512, 2)
void blk_attn(const float* __restrict__ Q, const float* __restrict__ K,
              const float* __restrict__ V, const float* __restrict__ M,
              float* __restrict__ O) {
    int bid = blockIdx.x;
    bid = (bid & 7) * 192 + (bid >> 3);   // XCD-aware bijective swizzle (1536 % 8 == 0)

    const int j  = bid & 31;   // 128-query group
    const int bh = bid >> 5;
    const int b  = bh / NH;

    const size_t base = (size_t)bh * SEQ * DIM;
    const float* Qp = Q + base + (size_t)j * 128 * DIM;
    const float* Kp = K + base;
    const float* Vp = V + base;
    const float* Mp = M + (size_t)b * SEQ;
    float*       Op = O + base + (size_t)j * 128 * DIM;

    const int tid  = threadIdx.x;
    const int wv   = tid >> 6;     // wave 0..7, owns queries [16wv,16wv+16)
    const int lane = tid & 63;
    const int lo   = lane & 15;
    const int hi   = lane >> 4;

    // union key-span: [kb0, kb0+384); windows = tiles [0,16) and [8,24)
    const int  kb0  = (j == 0) ? 0 : 128 * j - 128;
    const bool mid  = (j != 0) && (j != 31);
    const float wt0 = mid ? 0.5f : 1.0f;

    // 112 KB LDS -> 1 block/CU, 8 waves. All b128 reads conflict-free (XOR swz).
    __shared__ unsigned short Ks[384][64];   // Ks[key][d ^ 8*(key&7)]
    __shared__ unsigned short Vt[64][384];   // Vt[d][key ^ 8*(d&7)]
    __shared__ unsigned short Pw[8][16][64]; // Pw[wv][q][col ^ 8*(q&7)]

    // ---- Q fragments (scaled by 1/sqrt(64)), in regs ----
    short8 qa[2];
    {
        const float* qr = Qp + (size_t)(wv * 16 + lo) * DIM + hi * 8;
        #pragma unroll
        for (int s = 0; s < 2; ++s) {
            f32x4 a = *reinterpret_cast<const f32x4*>(qr + 32 * s);
            f32x4 c = *reinterpret_cast<const f32x4*>(qr + 32 * s + 4);
            short8 t;
            t[0] = (short)f2bf(a[0] * 0.125f);
            t[1] = (short)f2bf(a[1] * 0.125f);
            t[2] = (short)f2bf(a[2] * 0.125f);
            t[3] = (short)f2bf(a[3] * 0.125f);
            t[4] = (short)f2bf(c[0] * 0.125f);
            t[5] = (short)f2bf(c[1] * 0.125f);
            t[6] = (short)f2bf(c[2] * 0.125f);
            t[7] = (short)f2bf(c[3] * 0.125f);
            qa[s] = t;
        }
    }

    // ---- stage K: 384 rows, vectorized conflict-free writes ----
    {
        const int kc  = lane & 15;          // col-quad
        const int krb = tid >> 4;           // 0..31
        #pragma unroll
        for (int rr = 0; rr < 12; ++rr) {
            const int row = krb + 32 * rr;              // span-local
            int krow = kb0 + row; krow = krow < SEQ ? krow : SEQ - 1;
            f32x4 kv = *reinterpret_cast<const f32x4*>(Kp + (size_t)krow * DIM + 4 * kc);
            ushort4v kk;
            kk[0] = f2bf(kv[0]); kk[1] = f2bf(kv[1]);
            kk[2] = f2bf(kv[2]); kk[3] = f2bf(kv[3]);
            *reinterpret_cast<ushort4v*>(&Ks[row][(4 * kc) ^ (8 * (row & 7))]) = kk;
        }
    }
    // ---- stage V: 4x4 register transpose, b64 writes along keys ----
    {
        const int vc  = lane >> 2;          // d-quad 0..15
        const int vrk = lane & 3;
        #pragma unroll
        for (int it = 0; it < 3; ++it) {
            const int k0 = 4 * (vrk + 4 * wv + 32 * it);   // span-local, 4-aligned
            f32x4 vvr[4];
            #pragma unroll
            for (int kk = 0; kk < 4; ++kk) {
                int krow = kb0 + k0 + kk; krow = krow < SEQ ? krow : SEQ - 1;
                vvr[kk] = *reinterpret_cast<const f32x4*>(Vp + (size_t)krow * DIM + 4 * vc);
            }
            #pragma unroll
            for (int i = 0; i < 4; ++i) {
                const int d = 4 * vc + i;
                ushort4v o;
                o[0] = f2bf(vvr[0][i]); o[1] = f2bf(vvr[1][i]);
                o[2] = f2bf(vvr[2][i]); o[3] = f2bf(vvr[3][i]);
                *reinterpret_cast<ushort4v*>(&Vt[d][k0 ^ (8 * (d & 7))]) = o;
            }
        }
    }
    __syncthreads();   // the only block barrier

    // ---- QK^T over 24 key-tiles ----
    f32x4 st[24];
    #pragma unroll
    for (int t = 0; t < 24; ++t) { st[t][0]=0.f; st[t][1]=0.f; st[t][2]=0.f; st[t][3]=0.f; }
    __builtin_amdgcn_s_setprio(1);
    #pragma unroll
    for (int s = 0; s < 2; ++s) {
        #pragma unroll
        for (int t = 0; t < 24; ++t) {
            short8 kf = *reinterpret_cast<const short8*>(
                &Ks[t * 16 + lo][(s * 32 + hi * 8) ^ (8 * (lo & 7))]);
            st[t] = __builtin_amdgcn_mfma_f32_16x16x32_bf16(qa[s], kf, st[t], 0, 0, 0);
        }
    }
    __builtin_amdgcn_s_setprio(0);

    // ---- additive mask (per absolute key) ----
    #pragma unroll
    for (int t = 0; t < 24; ++t) {
        int km = kb0 + t * 16 + lo; km = km < SEQ ? km : SEQ - 1;
        const float mv = Mp[km];
        #pragma unroll
        for (int r = 0; r < 4; ++r) st[t][r] += mv;
    }

    // ---- softmax stats: window0 = tiles 0..15, window1 = tiles 8..23 ----
    float m0[4], m1[4], d0[4], d1[4], c0[4], c1[4];
    #pragma unroll
    for (int r = 0; r < 4; ++r) {
        float a = st[0][r];
        #pragma unroll
        for (int t = 1; t < 16; ++t) a = fmaxf(a, st[t][r]);
        a = fmaxf(a, __shfl_xor(a, 1)); a = fmaxf(a, __shfl_xor(a, 2));
        a = fmaxf(a, __shfl_xor(a, 4)); a = fmaxf(a, __shfl_xor(a, 8));
        m0[r] = a;
        float c = st[8][r];
        #pragma unroll
        for (int t = 9; t < 24; ++t) c = fmaxf(c, st[t][r]);
        c = fmaxf(c, __shfl_xor(c, 1)); c = fmaxf(c, __shfl_xor(c, 2));
        c = fmaxf(c, __shfl_xor(c, 4)); c = fmaxf(c, __shfl_xor(c, 8));
        m1[r] = c;
    }
    #pragma unroll
    for (int r = 0; r < 4; ++r) {
        float s0 = 0.f, s1 = 0.f;
        #pragma unroll
        for (int t = 0; t < 16; ++t) s0 += __expf(st[t][r] - m0[r]);
        #pragma unroll
        for (int t = 8; t < 24; ++t) s1 += __expf(st[t][r] - m1[r]);
        s0 += __shfl_xor(s0, 1); s0 += __shfl_xor(s0, 2);
        s0 += __shfl_xor(s0, 4); s0 += __shfl_xor(s0, 8);
        s1 += __shfl_xor(s1, 1); s1 += __shfl_xor(s1, 2);
        s1 += __shfl_xor(s1, 4); s1 += __shfl_xor(s1, 8);
        d0[r] = s0; d1[r] = s1;
        c0[r] = wt0 / s0;
        c1[r] = mid ? 0.5f / s1 : 0.f;
    }

    // ---- single PV pass over 384 keys (P' pre-weighted, combines both windows) ----
    f32x4 acc[4];
    #pragma unroll
    for (int dt = 0; dt < 4; ++dt) { acc[dt][0]=0.f; acc[dt][1]=0.f; acc[dt][2]=0.f; acc[dt][3]=0.f; }

    #pragma unroll
    for (int kq = 0; kq < 6; ++kq) {
        #pragma unroll
        for (int tt = 0; tt < 4; ++tt) {
            const int t = 4 * kq + tt;
            #pragma unroll
            for (int r = 0; r < 4; ++r) {
                float p = 0.f;
                if (t < 16) p += c0[r] * __expf(st[t][r] - m0[r]);
                if (t >= 8) p += c1[r] * __expf(st[t][r] - m1[r]);
                const int q = 4 * hi + r;
                Pw[wv][q][(tt * 16 + lo) ^ (8 * (q & 7))] = f2bf(p);
            }
        }
        // per-wave DS in-order; compiler inserts lgkmcnt before dependent read
        __builtin_amdgcn_s_setprio(1);
        #pragma unroll
        for (int s = 0; s < 2; ++s) {
            short8 pf = *reinterpret_cast<const short8*>(
                &Pw[wv][lo][(s * 32 + hi * 8) ^ (8 * (lo & 7))]);
            #pragma unroll
            for (int dt = 0; dt < 4; ++dt) {
                short8 vf = *reinterpret_cast<const short8*>(
                    &Vt[dt * 16 + lo][(kq * 64 + s * 32 + hi * 8) ^ (8 * (lo & 7))]);
                acc[dt] = __builtin_amdgcn_mfma_f32_16x16x32_bf16(pf, vf, acc[dt], 0, 0, 0);
            }
        }
        __builtin_amdgcn_s_setprio(0);
    }

    // ---- write output (already weighted+normalized) ----
    #pragma unroll
    for (int dt = 0; dt < 4; ++dt)
        #pragma unroll
        for (int r = 0; r < 4; ++r)
            Op[(size_t)(wv * 16 + hi * 4 + r) * DIM + dt * 16 + lo] = acc[dt][r];
}

extern "C" void kernel_launch(void* const* d_in, const int* in_sizes, int n_in,
                              void* d_out, int out_size, void* d_ws, size_t ws_size,
                              hipStream_t stream) {
    const float* Q = (const float*)d_in[0];
    const float* K = (const float*)d_in[1];
    const float* V = (const float*)d_in[2];
    const float* M = (const float*)d_in[3];
    float* O = (float*)d_out;
    blk_attn<<<dim3(NB * NH * (SEQ / 128)), dim3(512), 0, stream>>>(Q, K, V, M, O);
}